// Round 3
// baseline (1976.431 us; speedup 1.0000x reference)
//
#include <hip/hip_runtime.h>

typedef unsigned int   u32;
typedef unsigned long long u64;

// ---------------- helpers ----------------
__device__ __forceinline__ float fast_tanh(float x) {
    x = fminf(fmaxf(x, -15.f), 15.f);
    float e = __expf(2.f * x);
    return __fdividef(e - 1.f, e + 1.f);
}

// ---------------- workspace layout (bytes, all fp32) ----------------
#define OF_X    ((size_t)0)
#define OF_XG   (OF_X  + 409600)
#define OF_H    (OF_XG + 3276800)
#define OF_X1   (OF_H  + 1638400)
#define OF_HV   (OF_X1 + 819200)
#define OF_P    (OF_HV + 819200)
#define OF_Q    (OF_P  + 1638400)

// ---------------- embedding ----------------
__global__ void embed_kernel(const int* __restrict__ words, const int* __restrict__ tags,
                             const float* __restrict__ wemb, const float* __restrict__ temb,
                             float* __restrict__ x) {
    int t = blockIdx.x;
    int w = words[t], tg = tags[t];
    for (int i = threadIdx.x; i < 400; i += 256) {
        float v = (i < 300) ? wemb[(size_t)w * 300 + i]
                            : temb[(size_t)tg * 100 + (i - 300)];
        x[(size_t)t * 400 + i] = v;
    }
}

// ---------------- tiled GEMM 64x64, 4x4 micro-tile ----------------
// C[t][n] = act( sum_k A[t][k]*B[n*ldb+boff+k] + b1[n]+b2[n] ), fp32.
__global__ __launch_bounds__(256)
void gemm_kernel(const float* __restrict__ A, int lda,
                 const float* __restrict__ B, int ldb, int boff,
                 const float* __restrict__ bias1, const float* __restrict__ bias2,
                 float* __restrict__ C, int ldc, int K, int act) {
    int t0 = blockIdx.x * 64;
    int n0 = blockIdx.y * 64;
    int tid = threadIdx.x;
    int tx = tid & 15, ty = tid >> 4;        // micro-tile: rows t0+ty*4.., cols n0+tx*4..
    int lr = tid >> 2, lk = (tid & 3) * 4;   // loader: row lr, k-offset lk
    __shared__ float As[16][68];
    __shared__ float Bs[16][68];
    float acc[4][4] = {};

    for (int k0 = 0; k0 < K; k0 += 16) {
        float4 av = *(const float4*)(A + (size_t)(t0 + lr) * lda + k0 + lk);
        float4 bv = *(const float4*)(B + (size_t)(n0 + lr) * ldb + boff + k0 + lk);
        __syncthreads();
        As[lk + 0][lr] = av.x; As[lk + 1][lr] = av.y; As[lk + 2][lr] = av.z; As[lk + 3][lr] = av.w;
        Bs[lk + 0][lr] = bv.x; Bs[lk + 1][lr] = bv.y; Bs[lk + 2][lr] = bv.z; Bs[lk + 3][lr] = bv.w;
        __syncthreads();
        #pragma unroll
        for (int kk = 0; kk < 16; ++kk) {
            float4 a4 = *(const float4*)&As[kk][ty * 4];
            float4 b4 = *(const float4*)&Bs[kk][tx * 4];
            acc[0][0] += a4.x * b4.x; acc[0][1] += a4.x * b4.y; acc[0][2] += a4.x * b4.z; acc[0][3] += a4.x * b4.w;
            acc[1][0] += a4.y * b4.x; acc[1][1] += a4.y * b4.y; acc[1][2] += a4.y * b4.z; acc[1][3] += a4.y * b4.w;
            acc[2][0] += a4.z * b4.x; acc[2][1] += a4.z * b4.y; acc[2][2] += a4.z * b4.z; acc[2][3] += a4.z * b4.w;
            acc[3][0] += a4.w * b4.x; acc[3][1] += a4.w * b4.y; acc[3][2] += a4.w * b4.z; acc[3][3] += a4.w * b4.w;
        }
    }
    float bs[4];
    #pragma unroll
    for (int j = 0; j < 4; ++j) {
        int n = n0 + tx * 4 + j;
        float b = 0.f;
        if (bias1) b += bias1[n];
        if (bias2) b += bias2[n];
        bs[j] = b;
    }
    #pragma unroll
    for (int i = 0; i < 4; ++i) {
        int t = t0 + ty * 4 + i;
        float4 o;
        o.x = acc[i][0] + bs[0]; o.y = acc[i][1] + bs[1];
        o.z = acc[i][2] + bs[2]; o.w = acc[i][3] + bs[3];
        if (act) { o.x = fast_tanh(o.x); o.y = fast_tanh(o.y); o.z = fast_tanh(o.z); o.w = fast_tanh(o.w); }
        *(float4*)(C + (size_t)t * ldc + n0 + tx * 4) = o;
    }
}

// ---------------- persistent distributed LSTM layer, barrier-free ----------------
// grid 2*50 blocks, 256 threads (4 waves). Wave w of block (d,wg) owns h-elements
// {wg*8+2w, wg*8+2w+1} -> 8 gate rows. Weights in REGISTERS (52 VGPR/lane).
// h(t-1) staged per-wave-private in LDS; no __syncthreads in the step loop.
// Sync: hist[d][t][j] = (u64(tag_base+t+1)<<32)|f32bits(h), relaxed agent atomics.
#define LSTM_G 50
__global__ __launch_bounds__(256)
void lstm_kernel(const float* __restrict__ Whh,   // (2,1600,400)
                 const float* __restrict__ h0,    // (4,400)
                 const float* __restrict__ c0,    // (4,400)
                 int hc_base,
                 const float* __restrict__ xg,    // (256,3200): [t][d*1600 + gaterow]
                 u64* __restrict__ hist,          // (2,256,400)
                 u32 tag_base) {
    const int T = 256;
    int bid = blockIdx.x;
    int d  = bid / LSTM_G;
    int wg = bid % LSTM_G;
    int a8 = wg * 8;
    int tid = threadIdx.x;
    int w = tid >> 6, lane = tid & 63;
    int c = lane & 7, r = lane >> 3;         // c: k-chunk, r: local gate row
    int gate = r >> 1, jj = r & 1;
    int gr = gate * 400 + a8 + 2 * w + jj;   // global gate row for this lane

    __shared__ float4 hp4[4][104];           // per-wave private h buffer (416 floats)
    float* hp = (float*)&hp4[w][0];

    // --- load this lane's weight slice into registers (once) ---
    float4 wv[13];
    const float* wrow = Whh + (size_t)d * 640000 + (size_t)gr * 400;
    #pragma unroll
    for (int i = 0; i < 13; ++i) {
        int k = 4 * (c + 8 * i);
        if (k + 3 < 400) {
            wv[i] = *(const float4*)(wrow + k);
        } else {
            float4 z;
            z.x = (k + 0 < 400) ? wrow[k + 0] : 0.f;
            z.y = (k + 1 < 400) ? wrow[k + 1] : 0.f;
            z.z = (k + 2 < 400) ? wrow[k + 2] : 0.f;
            z.w = (k + 3 < 400) ? wrow[k + 3] : 0.f;
            wv[i] = z;
        }
    }
    if (lane < 16) hp[400 + lane] = 0.f;     // zero pad (never rewritten)

    float c_state = 0.f;
    if (lane == 0 || lane == 8)
        c_state = c0[(hc_base + d) * 400 + a8 + 2 * w + jj];

    u64* hst = hist + (size_t)d * 102400;

    for (int t = 0; t < T; ++t) {
        int xt = d ? (T - 1 - t) : t;
        float xgv = xg[(size_t)xt * 3200 + d * 1600 + gr];   // prefetch, used post-reduce

        // --- stage h(t-1) into this wave's private buffer ---
        if (t == 0) {
            #pragma unroll
            for (int m = 0; m < 7; ++m) {
                int e = lane + 64 * m;
                if (e < 400) hp[e] = h0[(hc_base + d) * 400 + e];
            }
        } else {
            const u64* src = hst + (size_t)(t - 1) * 400;
            u32 want = tag_base + (u32)t;
            u64 vals[7];
            unsigned pend = 0;
            #pragma unroll
            for (int m = 0; m < 7; ++m)
                if (lane + 64 * m < 400) pend |= 1u << m;
            while (pend) {
                #pragma unroll
                for (int m = 0; m < 7; ++m)
                    if (pend & (1u << m))
                        vals[m] = __hip_atomic_load(&src[lane + 64 * m],
                                                    __ATOMIC_RELAXED, __HIP_MEMORY_SCOPE_AGENT);
                #pragma unroll
                for (int m = 0; m < 7; ++m)
                    if ((pend & (1u << m)) && (u32)(vals[m] >> 32) == want) {
                        hp[lane + 64 * m] = __uint_as_float((u32)vals[m]);
                        pend &= ~(1u << m);
                    }
            }
        }

        // --- dot: registers x private-LDS broadcast ---
        float s = 0.f;
        #pragma unroll
        for (int i = 0; i < 13; ++i) {
            float4 h4 = hp4[w][c + 8 * i];
            s += wv[i].x * h4.x + wv[i].y * h4.y + wv[i].z * h4.z + wv[i].w * h4.w;
        }
        // reduce over the 8 k-chunks (contiguous lanes within each row)
        s += __shfl_down(s, 4);
        s += __shfl_down(s, 2);
        s += __shfl_down(s, 1);

        float v = 0.f;
        if (c == 0) {   // lanes 0,8,16,24,32,40,48,56 hold row sums
            float tot = s + xgv;
            float arg = (gate == 2) ? 2.f * tot : -tot;
            arg = fminf(fmaxf(arg, -60.f), 60.f);
            float e = __expf(arg);
            v = (gate == 2) ? (e - 1.f) * __frcp_rn(e + 1.f)   // tanh
                            : __frcp_rn(1.f + e);              // sigmoid
        }
        float fv = __shfl(v, lane + 16);
        float gv = __shfl(v, lane + 32);
        float ov = __shfl(v, lane + 48);
        if (lane == 0 || lane == 8) {
            c_state = fv * c_state + v * gv;   // v = i-gate here
            float ec = __expf(fminf(fmaxf(2.f * c_state, -60.f), 60.f));
            float th = (ec - 1.f) * __frcp_rn(ec + 1.f);
            float h = ov * th;
            u64 pk = (((u64)(tag_base + t + 1)) << 32) | (u64)__float_as_uint(h);
            __hip_atomic_store(&hst[(size_t)t * 400 + a8 + 2 * w + jj], pk,
                               __ATOMIC_RELAXED, __HIP_MEMORY_SCOPE_AGENT);
        }
    }
}

// ---------------- gathers ----------------
__global__ void gather_bi_kernel(const u64* __restrict__ hist, float* __restrict__ out800) {
    int t = blockIdx.x;
    for (int cc = threadIdx.x; cc < 800; cc += 256) {
        u64 v = (cc < 400) ? hist[(size_t)t * 400 + cc]
                           : hist[(size_t)102400 + (size_t)(255 - t) * 400 + (cc - 400)];
        out800[(size_t)t * 800 + cc] = __uint_as_float((u32)v);
    }
}
__global__ void gather_lf_kernel(const float* __restrict__ hV, const int* __restrict__ arcs,
                                 float* __restrict__ LF) {
    int t = blockIdx.x;
    int head = arcs[1 + t];
    int idxt = min(max(head - 1, 0), 255);
    for (int cc = threadIdx.x; cc < 1600; cc += 256) {
        float v = (cc < 800) ? hV[(size_t)t * 800 + cc] : hV[(size_t)idxt * 800 + (cc - 800)];
        LF[(size_t)t * 1600 + cc] = v;
    }
}

// ---------------- arc pairwise scorer ----------------
__global__ __launch_bounds__(256)
void arc_kernel(const float* __restrict__ P, const float* __restrict__ Q,
                const float* __restrict__ Wa2, const float* __restrict__ ba2,
                float* __restrict__ out) {
    int i0 = blockIdx.x * 16, j0 = blockIdx.y * 16;
    int tid = threadIdx.x;
    int ii = tid >> 4, jj = tid & 15;
    __shared__ float Pt[16][65], Qt[16][65];
    __shared__ float W2f[1600];
    for (int m = tid; m < 1600; m += 256) W2f[m] = Wa2[m];
    __syncthreads();

    float acc = 0.f;
    int mm = tid & 63, r4 = tid >> 6;
    for (int m0 = 0; m0 < 1600; m0 += 64) {
        #pragma unroll
        for (int rr = r4; rr < 16; rr += 4) {
            Pt[rr][mm] = P[(size_t)(i0 + rr) * 1600 + m0 + mm];
            Qt[rr][mm] = Q[(size_t)(j0 + rr) * 1600 + m0 + mm];
        }
        __syncthreads();
        #pragma unroll 8
        for (int m = 0; m < 64; ++m) {
            float s = Pt[ii][m] + Qt[jj][m];
            acc += W2f[m0 + m] * fast_tanh(s);
        }
        __syncthreads();
    }
    float raw = acc + ba2[0];
    int gi = i0 + ii, gj = j0 + jj;
    if (gi == gj) raw = 0.f;
    out[(size_t)(gi + 1) * 257 + (gj + 1)] = raw;
}

__global__ void border_kernel(float* __restrict__ out) {
    int t = threadIdx.x;
    if (t < 257) out[t] = (t == 0) ? 1.0f : 0.0f;
    if (t >= 1 && t < 257) out[(size_t)t * 257] = 0.0f;
}

// ---------------- label output ----------------
__global__ __launch_bounds__(256)
void label_out_kernel(const float* __restrict__ U, const float* __restrict__ Wl2,
                      const float* __restrict__ bl2, const int* __restrict__ arcs,
                      float* __restrict__ out) {
    int t = blockIdx.x;
    __shared__ float u_l[1600];
    __shared__ float part[4][64];
    for (int m = threadIdx.x; m < 1600; m += 256) u_l[m] = U[(size_t)t * 1600 + m];
    __syncthreads();
    int tid = threadIdx.x;
    int n = tid & 63, p = tid >> 6;
    float acc = 0.f;
    if (n < 40) {
        const float4* wr4 = (const float4*)(Wl2 + (size_t)n * 1600 + p * 400);
        const float*  ub  = u_l + p * 400;
        for (int m = 0; m < 100; ++m) {
            float4 w = wr4[m];
            acc += ub[4*m] * w.x + ub[4*m+1] * w.y + ub[4*m+2] * w.z + ub[4*m+3] * w.w;
        }
    }
    part[p][n] = acc;
    __syncthreads();
    if (tid < 40) {
        float v = part[0][tid] + part[1][tid] + part[2][tid] + part[3][tid] + bl2[tid];
        if (arcs[1 + t] == 0) v = 0.f;
        out[(size_t)t * 40 + tid] = v;
    }
}

// ---------------- launch ----------------
extern "C" void kernel_launch(void* const* d_in, const int* in_sizes, int n_in,
                              void* d_out, int out_size, void* d_ws, size_t ws_size,
                              hipStream_t stream) {
    const int*   words = (const int*)d_in[0];
    const int*   tags  = (const int*)d_in[1];
    const int*   arcs  = (const int*)d_in[2];
    const float* h0    = (const float*)d_in[3];
    const float* c0    = (const float*)d_in[4];
    const float* wemb  = (const float*)d_in[5];
    const float* temb  = (const float*)d_in[6];
    const float* Wih0  = (const float*)d_in[7];
    const float* Whh0  = (const float*)d_in[8];
    const float* bih0  = (const float*)d_in[9];
    const float* bhh0  = (const float*)d_in[10];
    const float* Wih1  = (const float*)d_in[11];
    const float* Whh1  = (const float*)d_in[12];
    const float* bih1  = (const float*)d_in[13];
    const float* bhh1  = (const float*)d_in[14];
    const float* Wa1   = (const float*)d_in[15];
    const float* ba1   = (const float*)d_in[16];
    const float* Wa2   = (const float*)d_in[17];
    const float* ba2   = (const float*)d_in[18];
    const float* Wl1   = (const float*)d_in[19];
    const float* bl1   = (const float*)d_in[20];
    const float* Wl2   = (const float*)d_in[21];
    const float* bl2   = (const float*)d_in[22];
    float* out = (float*)d_out;

    char* ws = (char*)d_ws;
    float* x    = (float*)(ws + OF_X);
    float* xg   = (float*)(ws + OF_XG);
    u64*   hist = (u64*)  (ws + OF_H);
    float* x1   = (float*)(ws + OF_X1);
    float* hV   = (float*)(ws + OF_HV);
    float* P    = (float*)(ws + OF_P);
    float* Q    = (float*)(ws + OF_Q);
    float* LF   = P;   // alias: P dead after arc_kernel
    float* U    = Q;   // alias: Q dead after arc_kernel

    hipMemsetAsync(hist, 0, 1638400, stream);

    embed_kernel<<<256, 256, 0, stream>>>(words, tags, wemb, temb, x);
    gemm_kernel<<<dim3(4, 50), 256, 0, stream>>>(x, 400, Wih0, 400, 0, bih0, bhh0, xg, 3200, 400, 0);
    lstm_kernel<<<2 * LSTM_G, 256, 0, stream>>>(Whh0, h0, c0, 0, xg, hist, 0u);
    gather_bi_kernel<<<256, 256, 0, stream>>>(hist, x1);
    gemm_kernel<<<dim3(4, 50), 256, 0, stream>>>(x1, 800, Wih1, 800, 0, bih1, bhh1, xg, 3200, 800, 0);
    lstm_kernel<<<2 * LSTM_G, 256, 0, stream>>>(Whh1, h0, c0, 2, xg, hist, 256u);
    gather_bi_kernel<<<256, 256, 0, stream>>>(hist, hV);
    gemm_kernel<<<dim3(4, 25), 256, 0, stream>>>(hV, 800, Wa1, 1600, 0,   ba1,    nullptr, P, 1600, 800, 0);
    gemm_kernel<<<dim3(4, 25), 256, 0, stream>>>(hV, 800, Wa1, 1600, 800, nullptr, nullptr, Q, 1600, 800, 0);
    arc_kernel<<<dim3(16, 16), 256, 0, stream>>>(P, Q, Wa2, ba2, out);
    border_kernel<<<1, 320, 0, stream>>>(out);
    gather_lf_kernel<<<256, 256, 0, stream>>>(hV, arcs, LF);
    gemm_kernel<<<dim3(4, 25), 256, 0, stream>>>(LF, 1600, Wl1, 1600, 0, bl1, nullptr, U, 1600, 1600, 1);
    label_out_kernel<<<256, 256, 0, stream>>>(U, Wl2, bl2, arcs, out + 66049);
}

// Round 4
// 1342.808 us; speedup vs baseline: 1.4719x; 1.4719x over previous
//
#include <hip/hip_runtime.h>

typedef unsigned int   u32;
typedef unsigned long long u64;

// ---------------- helpers ----------------
__device__ __forceinline__ float fast_tanh(float x) {
    x = fminf(fmaxf(x, -15.f), 15.f);
    float e = __expf(2.f * x);
    return __fdividef(e - 1.f, e + 1.f);
}

// ---------------- workspace layout (bytes, all fp32) ----------------
// x: 256x400; xg: 256x3200; hist: 2x256x400 u64 (tag-versioned, reused by both layers);
// P,Q,U: 256x1600. Total ~10.2 MB.
#define OF_X    ((size_t)0)
#define OF_XG   (OF_X  + 409600)
#define OF_H    (OF_XG + 3276800)
#define OF_P    (OF_H  + 1638400)
#define OF_Q    (OF_P  + 1638400)
#define OF_U    (OF_Q  + 1638400)

// read 4 consecutive hV elements (t, k..k+3), k%4==0, from tagged hist
// hV[t][k] = lo32(hist[t*400+k]) for k<400, lo32(hist[102400+(255-t)*400+k-400]) else
__device__ __forceinline__ float4 hist4(const u64* __restrict__ hist, int t, int k) {
    const u64* p = (k < 400) ? hist + (size_t)t * 400 + k
                             : hist + 102400 + (size_t)(255 - t) * 400 + (k - 400);
    ulonglong2 a = *(const ulonglong2*)p;
    ulonglong2 b = *(const ulonglong2*)(p + 2);
    return make_float4(__uint_as_float((u32)a.x), __uint_as_float((u32)a.y),
                       __uint_as_float((u32)b.x), __uint_as_float((u32)b.y));
}

// ---------------- embedding ----------------
__global__ void embed_kernel(const int* __restrict__ words, const int* __restrict__ tags,
                             const float* __restrict__ wemb, const float* __restrict__ temb,
                             float* __restrict__ x) {
    int t = blockIdx.x;
    int w = words[t], tg = tags[t];
    for (int i = threadIdx.x; i < 400; i += 256) {
        float v = (i < 300) ? wemb[(size_t)w * 300 + i]
                            : temb[(size_t)tg * 100 + (i - 300)];
        x[(size_t)t * 400 + i] = v;
    }
}

// ---------------- tiled GEMM 64x64, 4x4 micro-tile (A = plain fp32) ----------------
__global__ __launch_bounds__(256)
void gemm_kernel(const float* __restrict__ A, int lda,
                 const float* __restrict__ B, int ldb, int boff,
                 const float* __restrict__ bias1, const float* __restrict__ bias2,
                 float* __restrict__ C, int ldc, int K, int act) {
    int t0 = blockIdx.x * 64;
    int n0 = blockIdx.y * 64;
    int tid = threadIdx.x;
    int tx = tid & 15, ty = tid >> 4;
    int lr = tid >> 2, lk = (tid & 3) * 4;
    __shared__ float As[16][68];
    __shared__ float Bs[16][68];
    float acc[4][4] = {};

    for (int k0 = 0; k0 < K; k0 += 16) {
        float4 av = *(const float4*)(A + (size_t)(t0 + lr) * lda + k0 + lk);
        float4 bv = *(const float4*)(B + (size_t)(n0 + lr) * ldb + boff + k0 + lk);
        __syncthreads();
        As[lk + 0][lr] = av.x; As[lk + 1][lr] = av.y; As[lk + 2][lr] = av.z; As[lk + 3][lr] = av.w;
        Bs[lk + 0][lr] = bv.x; Bs[lk + 1][lr] = bv.y; Bs[lk + 2][lr] = bv.z; Bs[lk + 3][lr] = bv.w;
        __syncthreads();
        #pragma unroll
        for (int kk = 0; kk < 16; ++kk) {
            float4 a4 = *(const float4*)&As[kk][ty * 4];
            float4 b4 = *(const float4*)&Bs[kk][tx * 4];
            acc[0][0] += a4.x * b4.x; acc[0][1] += a4.x * b4.y; acc[0][2] += a4.x * b4.z; acc[0][3] += a4.x * b4.w;
            acc[1][0] += a4.y * b4.x; acc[1][1] += a4.y * b4.y; acc[1][2] += a4.y * b4.z; acc[1][3] += a4.y * b4.w;
            acc[2][0] += a4.z * b4.x; acc[2][1] += a4.z * b4.y; acc[2][2] += a4.z * b4.z; acc[2][3] += a4.z * b4.w;
            acc[3][0] += a4.w * b4.x; acc[3][1] += a4.w * b4.y; acc[3][2] += a4.w * b4.z; acc[3][3] += a4.w * b4.w;
        }
    }
    float bs[4];
    #pragma unroll
    for (int j = 0; j < 4; ++j) {
        int n = n0 + tx * 4 + j;
        float b = 0.f;
        if (bias1) b += bias1[n];
        if (bias2) b += bias2[n];
        bs[j] = b;
    }
    #pragma unroll
    for (int i = 0; i < 4; ++i) {
        int t = t0 + ty * 4 + i;
        float4 o;
        o.x = acc[i][0] + bs[0]; o.y = acc[i][1] + bs[1];
        o.z = acc[i][2] + bs[2]; o.w = acc[i][3] + bs[3];
        if (act) { o.x = fast_tanh(o.x); o.y = fast_tanh(o.y); o.z = fast_tanh(o.z); o.w = fast_tanh(o.w); }
        *(float4*)(C + (size_t)t * ldc + n0 + tx * 4) = o;
    }
}

// ---------------- GEMM with A read from tagged hist (hV on the fly) ----------------
// A[t][k] = hV[t][k] for k<800; if arcs!=null, A[t][k] = hV[clamp(arcs[1+t]-1)][k-800] for k>=800.
__global__ __launch_bounds__(256)
void gemm_hist_kernel(const u64* __restrict__ hist, const int* __restrict__ arcs,
                      const float* __restrict__ B, int ldb, int boff,
                      const float* __restrict__ bias1, const float* __restrict__ bias2,
                      float* __restrict__ C, int ldc, int K, int act) {
    int t0 = blockIdx.x * 64;
    int n0 = blockIdx.y * 64;
    int tid = threadIdx.x;
    int tx = tid & 15, ty = tid >> 4;
    int lr = tid >> 2, lk = (tid & 3) * 4;
    __shared__ float As[16][68];
    __shared__ float Bs[16][68];
    float acc[4][4] = {};

    int t = t0 + lr;
    int tind = t;
    if (arcs) {
        int h = arcs[1 + t];
        tind = min(max(h - 1, 0), 255);
    }

    for (int k0 = 0; k0 < K; k0 += 16) {
        int k = k0 + lk;
        int tt = (k < 800) ? t : tind;
        int kk2 = (k < 800) ? k : k - 800;
        float4 av = hist4(hist, tt, kk2);
        float4 bv = *(const float4*)(B + (size_t)(n0 + lr) * ldb + boff + k0 + lk);
        __syncthreads();
        As[lk + 0][lr] = av.x; As[lk + 1][lr] = av.y; As[lk + 2][lr] = av.z; As[lk + 3][lr] = av.w;
        Bs[lk + 0][lr] = bv.x; Bs[lk + 1][lr] = bv.y; Bs[lk + 2][lr] = bv.z; Bs[lk + 3][lr] = bv.w;
        __syncthreads();
        #pragma unroll
        for (int kk = 0; kk < 16; ++kk) {
            float4 a4 = *(const float4*)&As[kk][ty * 4];
            float4 b4 = *(const float4*)&Bs[kk][tx * 4];
            acc[0][0] += a4.x * b4.x; acc[0][1] += a4.x * b4.y; acc[0][2] += a4.x * b4.z; acc[0][3] += a4.x * b4.w;
            acc[1][0] += a4.y * b4.x; acc[1][1] += a4.y * b4.y; acc[1][2] += a4.y * b4.z; acc[1][3] += a4.y * b4.w;
            acc[2][0] += a4.z * b4.x; acc[2][1] += a4.z * b4.y; acc[2][2] += a4.z * b4.z; acc[2][3] += a4.z * b4.w;
            acc[3][0] += a4.w * b4.x; acc[3][1] += a4.w * b4.y; acc[3][2] += a4.w * b4.z; acc[3][3] += a4.w * b4.w;
        }
    }
    float bs[4];
    #pragma unroll
    for (int j = 0; j < 4; ++j) {
        int n = n0 + tx * 4 + j;
        float b = 0.f;
        if (bias1) b += bias1[n];
        if (bias2) b += bias2[n];
        bs[j] = b;
    }
    #pragma unroll
    for (int i = 0; i < 4; ++i) {
        int tr = t0 + ty * 4 + i;
        float4 o;
        o.x = acc[i][0] + bs[0]; o.y = acc[i][1] + bs[1];
        o.z = acc[i][2] + bs[2]; o.w = acc[i][3] + bs[3];
        if (act) { o.x = fast_tanh(o.x); o.y = fast_tanh(o.y); o.z = fast_tanh(o.z); o.w = fast_tanh(o.w); }
        *(float4*)(C + (size_t)tr * ldc + n0 + tx * 4) = o;
    }
}

// ---------------- persistent distributed LSTM: coop poll + reg weights ----------------
// grid 2*50 blocks, 256 threads (4 waves). Wave w of block (d,wg) owns h-elems
// {wg*8+2w, wg*8+2w+1} -> 8 gate rows; weights in registers (52 VGPR/lane).
// h(t-1): cooperative block poll (<=2 slots/thread) into double-buffered LDS,
// ONE __syncthreads per step. Sync: hist[d][t][j] = (u64(tag)<<32)|f32bits(h).
// Tag domains: layer0 wants 1..256, layer1 wants 257..512, poison=0xAAAAAAAA — disjoint.
#define LSTM_G 50
__global__ __launch_bounds__(256)
void lstm_kernel(const float* __restrict__ Whh,   // (2,1600,400)
                 const float* __restrict__ h0,    // (4,400)
                 const float* __restrict__ c0,    // (4,400)
                 int hc_base,
                 const float* __restrict__ xg,    // (256,3200): [t][d*1600 + gaterow]
                 u64* __restrict__ hist,          // (2,256,400)
                 u32 tag_base) {
    const int T = 256;
    int bid = blockIdx.x;
    int d  = bid / LSTM_G;
    int wg = bid % LSTM_G;
    int a8 = wg * 8;
    int tid = threadIdx.x;
    int w = tid >> 6, lane = tid & 63;
    int c = lane & 7, r = lane >> 3;         // c: k-chunk, r: local gate row
    int gate = r >> 1, jj = r & 1;
    int gr = gate * 400 + a8 + 2 * w + jj;   // global gate row for this lane

    __shared__ float hbuf[2][416];           // double-buffered shared h (+16 zero pad)

    // --- weights into registers (once) ---
    float4 wv[13];
    const float* wrow = Whh + (size_t)d * 640000 + (size_t)gr * 400;
    #pragma unroll
    for (int i = 0; i < 13; ++i) {
        int k = 4 * (c + 8 * i);
        if (k + 3 < 400) {
            wv[i] = *(const float4*)(wrow + k);
        } else {
            wv[i] = make_float4(0.f, 0.f, 0.f, 0.f);
        }
    }
    if (tid < 16) { hbuf[0][400 + tid] = 0.f; hbuf[1][400 + tid] = 0.f; }

    float c_state = 0.f;
    if (lane == 0 || lane == 8)
        c_state = c0[(hc_base + d) * 400 + a8 + 2 * w + jj];

    u64* hst = hist + (size_t)d * 102400;
    bool need2 = (tid + 256 < 400);

    for (int t = 0; t < T; ++t) {
        int xt = d ? (T - 1 - t) : t;
        float xgv = xg[(size_t)xt * 3200 + d * 1600 + gr];
        float* hb = hbuf[t & 1];

        if (t == 0) {
            hb[tid] = h0[(hc_base + d) * 400 + tid];
            if (need2) hb[tid + 256] = h0[(hc_base + d) * 400 + tid + 256];
        } else {
            const u64* src = hst + (size_t)(t - 1) * 400;
            u32 want = tag_base + (u32)t;
            bool d1 = false, d2 = !need2;
            while (!(d1 && d2)) {
                u64 v1 = 0, v2 = 0;
                if (!d1) v1 = __hip_atomic_load(&src[tid], __ATOMIC_RELAXED, __HIP_MEMORY_SCOPE_AGENT);
                if (!d2) v2 = __hip_atomic_load(&src[tid + 256], __ATOMIC_RELAXED, __HIP_MEMORY_SCOPE_AGENT);
                if (!d1 && (u32)(v1 >> 32) == want) { hb[tid] = __uint_as_float((u32)v1); d1 = true; }
                if (!d2 && (u32)(v2 >> 32) == want) { hb[tid + 256] = __uint_as_float((u32)v2); d2 = true; }
            }
        }
        __syncthreads();   // sole barrier per step (double buffer makes it sufficient)

        const float4* h4 = (const float4*)hb;
        float s = 0.f;
        #pragma unroll
        for (int i = 0; i < 13; ++i) {
            float4 hv = h4[c + 8 * i];
            s += wv[i].x * hv.x + wv[i].y * hv.y + wv[i].z * hv.z + wv[i].w * hv.w;
        }
        s += __shfl_down(s, 4);
        s += __shfl_down(s, 2);
        s += __shfl_down(s, 1);

        float v = 0.f;
        if (c == 0) {   // lanes 0,8,..,56 hold the 8 gate-row sums
            float tot = s + xgv;
            float arg = (gate == 2) ? 2.f * tot : -tot;
            arg = fminf(fmaxf(arg, -60.f), 60.f);
            float e = __expf(arg);
            v = (gate == 2) ? (e - 1.f) * __frcp_rn(e + 1.f)   // tanh
                            : __frcp_rn(1.f + e);              // sigmoid
        }
        float fv = __shfl(v, lane + 16);
        float gv = __shfl(v, lane + 32);
        float ov = __shfl(v, lane + 48);
        if (lane == 0 || lane == 8) {
            c_state = fv * c_state + v * gv;   // v = i-gate here
            float ec = __expf(fminf(fmaxf(2.f * c_state, -60.f), 60.f));
            float th = (ec - 1.f) * __frcp_rn(ec + 1.f);
            float h = ov * th;
            u64 pk = (((u64)(tag_base + t + 1)) << 32) | (u64)__float_as_uint(h);
            __hip_atomic_store(&hst[(size_t)t * 400 + a8 + 2 * w + jj], pk,
                               __ATOMIC_RELAXED, __HIP_MEMORY_SCOPE_AGENT);
        }
    }
}

// ---------------- arc pairwise scorer ----------------
__global__ __launch_bounds__(256)
void arc_kernel(const float* __restrict__ P, const float* __restrict__ Q,
                const float* __restrict__ Wa2, const float* __restrict__ ba2,
                float* __restrict__ out) {
    int i0 = blockIdx.x * 16, j0 = blockIdx.y * 16;
    int tid = threadIdx.x;
    int ii = tid >> 4, jj = tid & 15;
    __shared__ float Pt[16][65], Qt[16][65];
    __shared__ float W2f[1600];
    for (int m = tid; m < 1600; m += 256) W2f[m] = Wa2[m];
    __syncthreads();

    float acc = 0.f;
    int mm = tid & 63, r4 = tid >> 6;
    for (int m0 = 0; m0 < 1600; m0 += 64) {
        #pragma unroll
        for (int rr = r4; rr < 16; rr += 4) {
            Pt[rr][mm] = P[(size_t)(i0 + rr) * 1600 + m0 + mm];
            Qt[rr][mm] = Q[(size_t)(j0 + rr) * 1600 + m0 + mm];
        }
        __syncthreads();
        #pragma unroll 8
        for (int m = 0; m < 64; ++m) {
            float s = Pt[ii][m] + Qt[jj][m];
            acc += W2f[m0 + m] * fast_tanh(s);
        }
        __syncthreads();
    }
    float raw = acc + ba2[0];
    int gi = i0 + ii, gj = j0 + jj;
    if (gi == gj) raw = 0.f;
    out[(size_t)(gi + 1) * 257 + (gj + 1)] = raw;
}

__global__ void border_kernel(float* __restrict__ out) {
    int t = threadIdx.x;
    if (t < 257) out[t] = (t == 0) ? 1.0f : 0.0f;
    if (t >= 1 && t < 257) out[(size_t)t * 257] = 0.0f;
}

// ---------------- label output ----------------
__global__ __launch_bounds__(256)
void label_out_kernel(const float* __restrict__ U, const float* __restrict__ Wl2,
                      const float* __restrict__ bl2, const int* __restrict__ arcs,
                      float* __restrict__ out) {
    int t = blockIdx.x;
    __shared__ float u_l[1600];
    __shared__ float part[4][64];
    for (int m = threadIdx.x; m < 1600; m += 256) u_l[m] = U[(size_t)t * 1600 + m];
    __syncthreads();
    int tid = threadIdx.x;
    int n = tid & 63, p = tid >> 6;
    float acc = 0.f;
    if (n < 40) {
        const float4* wr4 = (const float4*)(Wl2 + (size_t)n * 1600 + p * 400);
        const float*  ub  = u_l + p * 400;
        for (int m = 0; m < 100; ++m) {
            float4 w = wr4[m];
            acc += ub[4*m] * w.x + ub[4*m+1] * w.y + ub[4*m+2] * w.z + ub[4*m+3] * w.w;
        }
    }
    part[p][n] = acc;
    __syncthreads();
    if (tid < 40) {
        float v = part[0][tid] + part[1][tid] + part[2][tid] + part[3][tid] + bl2[tid];
        if (arcs[1 + t] == 0) v = 0.f;
        out[(size_t)t * 40 + tid] = v;
    }
}

// ---------------- launch ----------------
extern "C" void kernel_launch(void* const* d_in, const int* in_sizes, int n_in,
                              void* d_out, int out_size, void* d_ws, size_t ws_size,
                              hipStream_t stream) {
    const int*   words = (const int*)d_in[0];
    const int*   tags  = (const int*)d_in[1];
    const int*   arcs  = (const int*)d_in[2];
    const float* h0    = (const float*)d_in[3];
    const float* c0    = (const float*)d_in[4];
    const float* wemb  = (const float*)d_in[5];
    const float* temb  = (const float*)d_in[6];
    const float* Wih0  = (const float*)d_in[7];
    const float* Whh0  = (const float*)d_in[8];
    const float* bih0  = (const float*)d_in[9];
    const float* bhh0  = (const float*)d_in[10];
    const float* Wih1  = (const float*)d_in[11];
    const float* Whh1  = (const float*)d_in[12];
    const float* bih1  = (const float*)d_in[13];
    const float* bhh1  = (const float*)d_in[14];
    const float* Wa1   = (const float*)d_in[15];
    const float* ba1   = (const float*)d_in[16];
    const float* Wa2   = (const float*)d_in[17];
    const float* ba2   = (const float*)d_in[18];
    const float* Wl1   = (const float*)d_in[19];
    const float* bl1   = (const float*)d_in[20];
    const float* Wl2   = (const float*)d_in[21];
    const float* bl2   = (const float*)d_in[22];
    float* out = (float*)d_out;

    char* ws = (char*)d_ws;
    float* x    = (float*)(ws + OF_X);
    float* xg   = (float*)(ws + OF_XG);
    u64*   hist = (u64*)  (ws + OF_H);
    float* P    = (float*)(ws + OF_P);
    float* Q    = (float*)(ws + OF_Q);
    float* U    = (float*)(ws + OF_U);

    embed_kernel<<<256, 256, 0, stream>>>(words, tags, wemb, temb, x);
    gemm_kernel<<<dim3(4, 50), 256, 0, stream>>>(x, 400, Wih0, 400, 0, bih0, bhh0, xg, 3200, 400, 0);
    lstm_kernel<<<2 * LSTM_G, 256, 0, stream>>>(Whh0, h0, c0, 0, xg, hist, 0u);
    gemm_hist_kernel<<<dim3(4, 50), 256, 0, stream>>>(hist, nullptr, Wih1, 800, 0, bih1, bhh1, xg, 3200, 800, 0);
    lstm_kernel<<<2 * LSTM_G, 256, 0, stream>>>(Whh1, h0, c0, 2, xg, hist, 256u);
    gemm_hist_kernel<<<dim3(4, 25), 256, 0, stream>>>(hist, nullptr, Wa1, 1600, 0,   ba1,    nullptr, P, 1600, 800, 0);
    gemm_hist_kernel<<<dim3(4, 25), 256, 0, stream>>>(hist, nullptr, Wa1, 1600, 800, nullptr, nullptr, Q, 1600, 800, 0);
    arc_kernel<<<dim3(16, 16), 256, 0, stream>>>(P, Q, Wa2, ba2, out);
    border_kernel<<<1, 320, 0, stream>>>(out);
    gemm_hist_kernel<<<dim3(4, 25), 256, 0, stream>>>(hist, arcs, Wl1, 1600, 0, bl1, nullptr, U, 1600, 1600, 1);
    label_out_kernel<<<256, 256, 0, stream>>>(U, Wl2, bl2, arcs, out + 66049);
}

// Round 5
// 1273.486 us; speedup vs baseline: 1.5520x; 1.0544x over previous
//
#include <hip/hip_runtime.h>

typedef unsigned int   u32;
typedef unsigned long long u64;

// ---------------- helpers ----------------
__device__ __forceinline__ float fast_tanh(float x) {
    x = fminf(fmaxf(x, -15.f), 15.f);
    float e = __expf(2.f * x);
    return __fdividef(e - 1.f, e + 1.f);
}

// ---------------- workspace layout (bytes, all fp32) ----------------
// xg: 256x3200 (shared by both layers); hist: 2x256x400 u64 (tag-versioned, both layers);
// PQ: 256x3200 (P = cols 0..1599, Q = cols 1600..3199); U: 256x1600.
#define OF_XG   ((size_t)0)
#define OF_H    (OF_XG + 3276800)
#define OF_PQ   (OF_H  + 1638400)
#define OF_U    (OF_PQ + 3276800)

// read 4 consecutive hV elements (t, k..k+3), k%4==0, from tagged hist
__device__ __forceinline__ float4 hist4(const u64* __restrict__ hist, int t, int k) {
    const u64* p = (k < 400) ? hist + (size_t)t * 400 + k
                             : hist + 102400 + (size_t)(255 - t) * 400 + (k - 400);
    ulonglong2 a = *(const ulonglong2*)p;
    ulonglong2 b = *(const ulonglong2*)(p + 2);
    return make_float4(__uint_as_float((u32)a.x), __uint_as_float((u32)a.y),
                       __uint_as_float((u32)b.x), __uint_as_float((u32)b.y));
}

// ---------------- GEMM with A gathered from embeddings (layer-0 xg) ----------------
// C[t][n] = sum_k A[t][k]*B[n*400+k] + b1[n]+b2[n];  A[t][k] = k<300 ? wemb[words[t]][k]
// : temb[tags[t]][k-300].  M=256, K=400, N=3200. grid (4,50), block 256.
__global__ __launch_bounds__(256)
void gemm_embed_kernel(const int* __restrict__ words, const int* __restrict__ tags,
                       const float* __restrict__ wemb, const float* __restrict__ temb,
                       const float* __restrict__ B,
                       const float* __restrict__ bias1, const float* __restrict__ bias2,
                       float* __restrict__ C) {
    int t0 = blockIdx.x * 64;
    int n0 = blockIdx.y * 64;
    int tid = threadIdx.x;
    int tx = tid & 15, ty = tid >> 4;
    int lr = tid >> 2, lk = (tid & 3) * 4;
    __shared__ float As[16][68];
    __shared__ float Bs[16][68];
    float acc[4][4] = {};

    int t = t0 + lr;
    const float* arow0 = wemb + (size_t)words[t] * 300;
    const float* arow1 = temb + (size_t)tags[t] * 100 - 300;   // indexed by k directly

    for (int k0 = 0; k0 < 400; k0 += 16) {
        int k = k0 + lk;   // 300 % 4 == 0, so each float4 stays in one table
        float4 av = (k < 300) ? *(const float4*)(arow0 + k) : *(const float4*)(arow1 + k);
        float4 bv = *(const float4*)(B + (size_t)(n0 + lr) * 400 + k);
        __syncthreads();
        As[lk + 0][lr] = av.x; As[lk + 1][lr] = av.y; As[lk + 2][lr] = av.z; As[lk + 3][lr] = av.w;
        Bs[lk + 0][lr] = bv.x; Bs[lk + 1][lr] = bv.y; Bs[lk + 2][lr] = bv.z; Bs[lk + 3][lr] = bv.w;
        __syncthreads();
        #pragma unroll
        for (int kk = 0; kk < 16; ++kk) {
            float4 a4 = *(const float4*)&As[kk][ty * 4];
            float4 b4 = *(const float4*)&Bs[kk][tx * 4];
            acc[0][0] += a4.x * b4.x; acc[0][1] += a4.x * b4.y; acc[0][2] += a4.x * b4.z; acc[0][3] += a4.x * b4.w;
            acc[1][0] += a4.y * b4.x; acc[1][1] += a4.y * b4.y; acc[1][2] += a4.y * b4.z; acc[1][3] += a4.y * b4.w;
            acc[2][0] += a4.z * b4.x; acc[2][1] += a4.z * b4.y; acc[2][2] += a4.z * b4.z; acc[2][3] += a4.z * b4.w;
            acc[3][0] += a4.w * b4.x; acc[3][1] += a4.w * b4.y; acc[3][2] += a4.w * b4.z; acc[3][3] += a4.w * b4.w;
        }
    }
    float bs[4];
    #pragma unroll
    for (int j = 0; j < 4; ++j) {
        int n = n0 + tx * 4 + j;
        bs[j] = bias1[n] + bias2[n];
    }
    #pragma unroll
    for (int i = 0; i < 4; ++i) {
        int tr = t0 + ty * 4 + i;
        float4 o;
        o.x = acc[i][0] + bs[0]; o.y = acc[i][1] + bs[1];
        o.z = acc[i][2] + bs[2]; o.w = acc[i][3] + bs[3];
        *(float4*)(C + (size_t)tr * 3200 + n0 + tx * 4) = o;
    }
}

// ---------------- GEMM with A read from tagged hist (hV on the fly) ----------------
// A[t][k] = hV[t][k] for k<800; if arcs!=null, A[t][k] = hV[clamp(arcs[1+t]-1)][k-800] for k>=800.
__global__ __launch_bounds__(256)
void gemm_hist_kernel(const u64* __restrict__ hist, const int* __restrict__ arcs,
                      const float* __restrict__ B, int ldb, int boff,
                      const float* __restrict__ bias1, const float* __restrict__ bias2,
                      float* __restrict__ C, int ldc, int K, int act) {
    int t0 = blockIdx.x * 64;
    int n0 = blockIdx.y * 64;
    int tid = threadIdx.x;
    int tx = tid & 15, ty = tid >> 4;
    int lr = tid >> 2, lk = (tid & 3) * 4;
    __shared__ float As[16][68];
    __shared__ float Bs[16][68];
    float acc[4][4] = {};

    int t = t0 + lr;
    int tind = t;
    if (arcs) {
        int h = arcs[1 + t];
        tind = min(max(h - 1, 0), 255);
    }

    for (int k0 = 0; k0 < K; k0 += 16) {
        int k = k0 + lk;
        int tt = (k < 800) ? t : tind;
        int kk2 = (k < 800) ? k : k - 800;
        float4 av = hist4(hist, tt, kk2);
        float4 bv = *(const float4*)(B + (size_t)(n0 + lr) * ldb + boff + k0 + lk);
        __syncthreads();
        As[lk + 0][lr] = av.x; As[lk + 1][lr] = av.y; As[lk + 2][lr] = av.z; As[lk + 3][lr] = av.w;
        Bs[lk + 0][lr] = bv.x; Bs[lk + 1][lr] = bv.y; Bs[lk + 2][lr] = bv.z; Bs[lk + 3][lr] = bv.w;
        __syncthreads();
        #pragma unroll
        for (int kk = 0; kk < 16; ++kk) {
            float4 a4 = *(const float4*)&As[kk][ty * 4];
            float4 b4 = *(const float4*)&Bs[kk][tx * 4];
            acc[0][0] += a4.x * b4.x; acc[0][1] += a4.x * b4.y; acc[0][2] += a4.x * b4.z; acc[0][3] += a4.x * b4.w;
            acc[1][0] += a4.y * b4.x; acc[1][1] += a4.y * b4.y; acc[1][2] += a4.y * b4.z; acc[1][3] += a4.y * b4.w;
            acc[2][0] += a4.z * b4.x; acc[2][1] += a4.z * b4.y; acc[2][2] += a4.z * b4.z; acc[2][3] += a4.z * b4.w;
            acc[3][0] += a4.w * b4.x; acc[3][1] += a4.w * b4.y; acc[3][2] += a4.w * b4.z; acc[3][3] += a4.w * b4.w;
        }
    }
    float bs[4];
    #pragma unroll
    for (int j = 0; j < 4; ++j) {
        int n = n0 + tx * 4 + j;
        float b = 0.f;
        if (bias1) b += bias1[n];
        if (bias2) b += bias2[n];
        bs[j] = b;
    }
    #pragma unroll
    for (int i = 0; i < 4; ++i) {
        int tr = t0 + ty * 4 + i;
        float4 o;
        o.x = acc[i][0] + bs[0]; o.y = acc[i][1] + bs[1];
        o.z = acc[i][2] + bs[2]; o.w = acc[i][3] + bs[3];
        if (act) { o.x = fast_tanh(o.x); o.y = fast_tanh(o.y); o.z = fast_tanh(o.z); o.w = fast_tanh(o.w); }
        *(float4*)(C + (size_t)tr * ldc + n0 + tx * 4) = o;
    }
}

// ---------------- fused P|Q GEMM from hist ----------------
// PQ[t][n] = n<1600 ? hV[t]@Wa1[n][:800] + ba1[n]  :  hV[t]@Wa1[n-1600][800:]
// M=256, K=800, N=3200, ldc=3200. grid (4,50).
__global__ __launch_bounds__(256)
void gemm_pq_kernel(const u64* __restrict__ hist, const float* __restrict__ Wa1,
                    const float* __restrict__ ba1, float* __restrict__ PQ) {
    int t0 = blockIdx.x * 64;
    int n0 = blockIdx.y * 64;
    int tid = threadIdx.x;
    int tx = tid & 15, ty = tid >> 4;
    int lr = tid >> 2, lk = (tid & 3) * 4;
    __shared__ float As[16][68];
    __shared__ float Bs[16][68];
    float acc[4][4] = {};

    int t = t0 + lr;
    int nn = n0 + lr;                        // uniform per thread: which B row + k-offset
    const float* brow = (nn < 1600) ? Wa1 + (size_t)nn * 1600
                                    : Wa1 + (size_t)(nn - 1600) * 1600 + 800;

    for (int k0 = 0; k0 < 800; k0 += 16) {
        float4 av = hist4(hist, t, k0 + lk);
        float4 bv = *(const float4*)(brow + k0 + lk);
        __syncthreads();
        As[lk + 0][lr] = av.x; As[lk + 1][lr] = av.y; As[lk + 2][lr] = av.z; As[lk + 3][lr] = av.w;
        Bs[lk + 0][lr] = bv.x; Bs[lk + 1][lr] = bv.y; Bs[lk + 2][lr] = bv.z; Bs[lk + 3][lr] = bv.w;
        __syncthreads();
        #pragma unroll
        for (int kk = 0; kk < 16; ++kk) {
            float4 a4 = *(const float4*)&As[kk][ty * 4];
            float4 b4 = *(const float4*)&Bs[kk][tx * 4];
            acc[0][0] += a4.x * b4.x; acc[0][1] += a4.x * b4.y; acc[0][2] += a4.x * b4.z; acc[0][3] += a4.x * b4.w;
            acc[1][0] += a4.y * b4.x; acc[1][1] += a4.y * b4.y; acc[1][2] += a4.y * b4.z; acc[1][3] += a4.y * b4.w;
            acc[2][0] += a4.z * b4.x; acc[2][1] += a4.z * b4.y; acc[2][2] += a4.z * b4.z; acc[2][3] += a4.z * b4.w;
            acc[3][0] += a4.w * b4.x; acc[3][1] += a4.w * b4.y; acc[3][2] += a4.w * b4.z; acc[3][3] += a4.w * b4.w;
        }
    }
    float bs[4];
    #pragma unroll
    for (int j = 0; j < 4; ++j) {
        int n = n0 + tx * 4 + j;
        bs[j] = (n < 1600) ? ba1[n] : 0.f;
    }
    #pragma unroll
    for (int i = 0; i < 4; ++i) {
        int tr = t0 + ty * 4 + i;
        float4 o;
        o.x = acc[i][0] + bs[0]; o.y = acc[i][1] + bs[1];
        o.z = acc[i][2] + bs[2]; o.w = acc[i][3] + bs[3];
        *(float4*)(PQ + (size_t)tr * 3200 + n0 + tx * 4) = o;
    }
}

// ---------------- persistent distributed LSTM (unchanged from R4) ----------------
#define LSTM_G 50
__global__ __launch_bounds__(256)
void lstm_kernel(const float* __restrict__ Whh,   // (2,1600,400)
                 const float* __restrict__ h0,    // (4,400)
                 const float* __restrict__ c0,    // (4,400)
                 int hc_base,
                 const float* __restrict__ xg,    // (256,3200): [t][d*1600 + gaterow]
                 u64* __restrict__ hist,          // (2,256,400)
                 u32 tag_base) {
    const int T = 256;
    int bid = blockIdx.x;
    int d  = bid / LSTM_G;
    int wg = bid % LSTM_G;
    int a8 = wg * 8;
    int tid = threadIdx.x;
    int w = tid >> 6, lane = tid & 63;
    int c = lane & 7, r = lane >> 3;
    int gate = r >> 1, jj = r & 1;
    int gr = gate * 400 + a8 + 2 * w + jj;

    __shared__ float hbuf[2][416];

    float4 wv[13];
    const float* wrow = Whh + (size_t)d * 640000 + (size_t)gr * 400;
    #pragma unroll
    for (int i = 0; i < 13; ++i) {
        int k = 4 * (c + 8 * i);
        wv[i] = (k + 3 < 400) ? *(const float4*)(wrow + k) : make_float4(0.f, 0.f, 0.f, 0.f);
    }
    if (tid < 16) { hbuf[0][400 + tid] = 0.f; hbuf[1][400 + tid] = 0.f; }

    float c_state = 0.f;
    if (lane == 0 || lane == 8)
        c_state = c0[(hc_base + d) * 400 + a8 + 2 * w + jj];

    u64* hst = hist + (size_t)d * 102400;
    bool need2 = (tid + 256 < 400);

    for (int t = 0; t < T; ++t) {
        int xt = d ? (T - 1 - t) : t;
        float xgv = xg[(size_t)xt * 3200 + d * 1600 + gr];
        float* hb = hbuf[t & 1];

        if (t == 0) {
            hb[tid] = h0[(hc_base + d) * 400 + tid];
            if (need2) hb[tid + 256] = h0[(hc_base + d) * 400 + tid + 256];
        } else {
            const u64* src = hst + (size_t)(t - 1) * 400;
            u32 want = tag_base + (u32)t;
            bool d1 = false, d2 = !need2;
            while (!(d1 && d2)) {
                u64 v1 = 0, v2 = 0;
                if (!d1) v1 = __hip_atomic_load(&src[tid], __ATOMIC_RELAXED, __HIP_MEMORY_SCOPE_AGENT);
                if (!d2) v2 = __hip_atomic_load(&src[tid + 256], __ATOMIC_RELAXED, __HIP_MEMORY_SCOPE_AGENT);
                if (!d1 && (u32)(v1 >> 32) == want) { hb[tid] = __uint_as_float((u32)v1); d1 = true; }
                if (!d2 && (u32)(v2 >> 32) == want) { hb[tid + 256] = __uint_as_float((u32)v2); d2 = true; }
            }
        }
        __syncthreads();

        const float4* h4 = (const float4*)hb;
        float s = 0.f;
        #pragma unroll
        for (int i = 0; i < 13; ++i) {
            float4 hv = h4[c + 8 * i];
            s += wv[i].x * hv.x + wv[i].y * hv.y + wv[i].z * hv.z + wv[i].w * hv.w;
        }
        s += __shfl_down(s, 4);
        s += __shfl_down(s, 2);
        s += __shfl_down(s, 1);

        float v = 0.f;
        if (c == 0) {
            float tot = s + xgv;
            float arg = (gate == 2) ? 2.f * tot : -tot;
            arg = fminf(fmaxf(arg, -60.f), 60.f);
            float e = __expf(arg);
            v = (gate == 2) ? (e - 1.f) * __frcp_rn(e + 1.f)
                            : __frcp_rn(1.f + e);
        }
        float fv = __shfl(v, lane + 16);
        float gv = __shfl(v, lane + 32);
        float ov = __shfl(v, lane + 48);
        if (lane == 0 || lane == 8) {
            c_state = fv * c_state + v * gv;
            float ec = __expf(fminf(fmaxf(2.f * c_state, -60.f), 60.f));
            float th = (ec - 1.f) * __frcp_rn(ec + 1.f);
            float h = ov * th;
            u64 pk = (((u64)(tag_base + t + 1)) << 32) | (u64)__float_as_uint(h);
            __hip_atomic_store(&hst[(size_t)t * 400 + a8 + 2 * w + jj], pk,
                               __ATOMIC_RELAXED, __HIP_MEMORY_SCOPE_AGENT);
        }
    }
}

// ---------------- arc pairwise scorer (+ borders, folded in) ----------------
// raw[i,j] = ba2 + sum_m Wa2[m]*tanh(P[i][m]+Q[j][m]); P = PQ[:, :1600], Q = PQ[:, 1600:].
__global__ __launch_bounds__(256)
void arc_kernel(const float* __restrict__ PQ,
                const float* __restrict__ Wa2, const float* __restrict__ ba2,
                float* __restrict__ out) {
    int i0 = blockIdx.x * 16, j0 = blockIdx.y * 16;
    int tid = threadIdx.x;
    int ii = tid >> 4, jj = tid & 15;
    __shared__ float Pt[16][65], Qt[16][65];
    __shared__ float W2f[1600];

    if (i0 == 0 && j0 == 0) {   // borders: row 0 (with [0,0]=1) and col 0
        if (tid < 257) out[tid] = (tid == 0) ? 1.0f : 0.0f;
        out[(size_t)(tid + 1) * 257] = 0.0f;
        if (tid == 0) out[0] = 1.0f;
    }
    for (int m = tid; m < 1600; m += 256) W2f[m] = Wa2[m];
    __syncthreads();

    float acc = 0.f;
    int mm = tid & 63, r4 = tid >> 6;
    for (int m0 = 0; m0 < 1600; m0 += 64) {
        #pragma unroll
        for (int rr = r4; rr < 16; rr += 4) {
            Pt[rr][mm] = PQ[(size_t)(i0 + rr) * 3200 + m0 + mm];
            Qt[rr][mm] = PQ[(size_t)(j0 + rr) * 3200 + 1600 + m0 + mm];
        }
        __syncthreads();
        #pragma unroll 8
        for (int m = 0; m < 64; ++m) {
            float s = Pt[ii][m] + Qt[jj][m];
            acc += W2f[m0 + m] * fast_tanh(s);
        }
        __syncthreads();
    }
    float raw = acc + ba2[0];
    int gi = i0 + ii, gj = j0 + jj;
    if (gi == gj) raw = 0.f;
    out[(size_t)(gi + 1) * 257 + (gj + 1)] = raw;
}

// ---------------- label output ----------------
__global__ __launch_bounds__(256)
void label_out_kernel(const float* __restrict__ U, const float* __restrict__ Wl2,
                      const float* __restrict__ bl2, const int* __restrict__ arcs,
                      float* __restrict__ out) {
    int t = blockIdx.x;
    __shared__ float u_l[1600];
    __shared__ float part[4][64];
    for (int m = threadIdx.x; m < 1600; m += 256) u_l[m] = U[(size_t)t * 1600 + m];
    __syncthreads();
    int tid = threadIdx.x;
    int n = tid & 63, p = tid >> 6;
    float acc = 0.f;
    if (n < 40) {
        const float4* wr4 = (const float4*)(Wl2 + (size_t)n * 1600 + p * 400);
        const float*  ub  = u_l + p * 400;
        for (int m = 0; m < 100; ++m) {
            float4 w = wr4[m];
            acc += ub[4*m] * w.x + ub[4*m+1] * w.y + ub[4*m+2] * w.z + ub[4*m+3] * w.w;
        }
    }
    part[p][n] = acc;
    __syncthreads();
    if (tid < 40) {
        float v = part[0][tid] + part[1][tid] + part[2][tid] + part[3][tid] + bl2[tid];
        if (arcs[1 + t] == 0) v = 0.f;
        out[(size_t)t * 40 + tid] = v;
    }
}

// ---------------- launch ----------------
extern "C" void kernel_launch(void* const* d_in, const int* in_sizes, int n_in,
                              void* d_out, int out_size, void* d_ws, size_t ws_size,
                              hipStream_t stream) {
    const int*   words = (const int*)d_in[0];
    const int*   tags  = (const int*)d_in[1];
    const int*   arcs  = (const int*)d_in[2];
    const float* h0    = (const float*)d_in[3];
    const float* c0    = (const float*)d_in[4];
    const float* wemb  = (const float*)d_in[5];
    const float* temb  = (const float*)d_in[6];
    const float* Wih0  = (const float*)d_in[7];
    const float* Whh0  = (const float*)d_in[8];
    const float* bih0  = (const float*)d_in[9];
    const float* bhh0  = (const float*)d_in[10];
    const float* Wih1  = (const float*)d_in[11];
    const float* Whh1  = (const float*)d_in[12];
    const float* bih1  = (const float*)d_in[13];
    const float* bhh1  = (const float*)d_in[14];
    const float* Wa1   = (const float*)d_in[15];
    const float* ba1   = (const float*)d_in[16];
    const float* Wa2   = (const float*)d_in[17];
    const float* ba2   = (const float*)d_in[18];
    const float* Wl1   = (const float*)d_in[19];
    const float* bl1   = (const float*)d_in[20];
    const float* Wl2   = (const float*)d_in[21];
    const float* bl2   = (const float*)d_in[22];
    float* out = (float*)d_out;

    char* ws = (char*)d_ws;
    float* xg   = (float*)(ws + OF_XG);
    u64*   hist = (u64*)  (ws + OF_H);
    float* PQ   = (float*)(ws + OF_PQ);
    float* U    = (float*)(ws + OF_U);

    gemm_embed_kernel<<<dim3(4, 50), 256, 0, stream>>>(words, tags, wemb, temb, Wih0, bih0, bhh0, xg);
    lstm_kernel<<<2 * LSTM_G, 256, 0, stream>>>(Whh0, h0, c0, 0, xg, hist, 0u);
    gemm_hist_kernel<<<dim3(4, 50), 256, 0, stream>>>(hist, nullptr, Wih1, 800, 0, bih1, bhh1, xg, 3200, 800, 0);
    lstm_kernel<<<2 * LSTM_G, 256, 0, stream>>>(Whh1, h0, c0, 2, xg, hist, 256u);
    gemm_pq_kernel<<<dim3(4, 50), 256, 0, stream>>>(hist, Wa1, ba1, PQ);
    arc_kernel<<<dim3(16, 16), 256, 0, stream>>>(PQ, Wa2, ba2, out);
    gemm_hist_kernel<<<dim3(4, 25), 256, 0, stream>>>(hist, arcs, Wl1, 1600, 0, bl1, nullptr, U, 1600, 1600, 1);
    label_out_kernel<<<256, 256, 0, stream>>>(U, Wl2, bl2, arcs, out + 66049);
}